// Round 6
// baseline (311.671 us; speedup 1.0000x reference)
//
#include <hip/hip_runtime.h>
#include <hip/hip_bf16.h>
#include <math.h>

// (B,Cin,H,W)=(8,128,64,64), Cout=256, K=3, stride=1, pad=1, dil=1
#define B_    8
#define CIN   128
#define Hx    64
#define Wx    64
#define COUT  256
#define HW    4096
#define KTOT  1152      // CIN*9
#define NOFF  18
#define M_    32768     // B*HW
#define OFFSEG (B_ * NOFF * HW)   // 589824 floats per cin-segment partial
#define KCH   18        // K-chunks per half (chunk = 32 k)

typedef short bf16x8 __attribute__((ext_vector_type(8)));
typedef float f32x4  __attribute__((ext_vector_type(4)));

static __device__ __forceinline__ short f2bf(float f) {
  __hip_bfloat16 h = __float2bfloat16(f);
  return *reinterpret_cast<short*>(&h);
}

// ---------------- K1: offset conv, 18 channels/thread, cin split 4-way (proven) ----------------
__global__ __launch_bounds__(256) void offset_conv_kernel(
    const float* __restrict__ x, const float* __restrict__ ow,
    const float* __restrict__ ob, float* __restrict__ offp) {
  int r = blockIdx.x & 127, seg = blockIdx.x >> 7;
  int v = r * 256 + threadIdx.x;            // 0..32767
  int wo = v & 63, ho = (v >> 6) & 63, b = v >> 12;
  int cin0 = seg * 32;
  float acc[18];
#pragma unroll
  for (int c = 0; c < 18; ++c) acc[c] = 0.f;
  const float* xb = x + (b * CIN + cin0) * HW;
  const float* wb = ow + cin0 * 9;          // ow[c*1152 + cin*9 + tap]
  for (int ci = 0; ci < 32; ++ci) {
    const float* xp = xb + ci * HW;
    float win[9];
#pragma unroll
    for (int ky = 0; ky < 3; ++ky) {
      int iy = ho - 1 + ky;
      bool rok = (iy >= 0) & (iy < Hx);
      const float* rowp = xp + iy * Wx;
#pragma unroll
      for (int kx = 0; kx < 3; ++kx) {
        int ix = wo - 1 + kx;
        win[ky * 3 + kx] = (rok & (ix >= 0) & (ix < Wx)) ? rowp[ix] : 0.f;
      }
    }
    const float* wp = wb + ci * 9;          // wave-uniform -> scalar loads
#pragma unroll
    for (int c = 0; c < 18; ++c) {
#pragma unroll
      for (int t = 0; t < 9; ++t)
        acc[c] = fmaf(win[t], wp[c * KTOT + t], acc[c]);
    }
  }
  float* op = offp + seg * OFFSEG + (b * NOFF) * HW + ho * 64 + wo;
#pragma unroll
  for (int c = 0; c < 18; ++c)
    op[c * HW] = acc[c] + ((seg == 0) ? ob[c] : 0.f);
}

// ---------------- K2: weight -> bf16 blocked Wb[kc][cout][32] ----------------
__global__ __launch_bounds__(256) void wt_cvt_kernel(
    const float* __restrict__ w, short* __restrict__ Wb) {
  int t = blockIdx.x * 256 + threadIdx.x;   // 294912
  int ki = t & 31;
  int cout = (t >> 5) & 255;
  int kc = t >> 13;                         // 0..35
  int k = kc * 32 + ki;
  int kk = k >> 7, cin = k & 127;
  Wb[t] = f2bf(w[(cout * CIN + cin) * 9 + kk]);
}

// ---------------- K3: bilinear coefficient tables (proven math) ----------------
// cidx[kk*M + m] = short4 spatial indices; cwt[kk*M + m] = float4 weights.
__global__ __launch_bounds__(256) void coeff_kernel(
    const float* __restrict__ offp, short4* __restrict__ cidx, float4* __restrict__ cwt) {
  int t = blockIdx.x * 256 + threadIdx.x;   // 9*32768
  int m = t & (M_ - 1);
  int kk = t >> 15;                         // 0..8
  int b = m >> 12, ho = (m >> 6) & 63, wo = m & 63;
  int base = (b * NOFF + 2 * kk) * HW + (m & 4095);
  float dy = offp[base] + offp[base + OFFSEG] + offp[base + 2 * OFFSEG] + offp[base + 3 * OFFSEG];
  int base2 = base + HW;
  float dx = offp[base2] + offp[base2 + OFFSEG] + offp[base2 + 2 * OFFSEG] + offp[base2 + 3 * OFFSEG];
  float sy = (float)(ho - 1 + kk / 3) + dy;
  float sx = (float)(wo - 1 + kk % 3) + dx;
  float fy = floorf(sy), fx = floorf(sx);
  int y0 = (int)fy, x0 = (int)fx;
  float wy = sy - fy, wx = sx - fx;
  int y1 = y0 + 1, x1 = x0 + 1;
  int cy0 = min(max(y0, 0), Hx - 1), cy1 = min(max(y1, 0), Hx - 1);
  int cx0 = min(max(x0, 0), Wx - 1), cx1 = min(max(x1, 0), Wx - 1);
  bool vy0 = (y0 >= 0) & (y0 < Hx), vy1 = (y1 >= 0) & (y1 < Hx);
  bool vx0 = (x0 >= 0) & (x0 < Wx), vx1 = (x1 >= 0) & (x1 < Wx);
  short4 id;
  id.x = (short)(cy0 * Wx + cx0); id.y = (short)(cy0 * Wx + cx1);
  id.z = (short)(cy1 * Wx + cx0); id.w = (short)(cy1 * Wx + cx1);
  float4 wv;
  wv.x = (vy0 && vx0) ? (1.f - wy) * (1.f - wx) : 0.f;
  wv.y = (vy0 && vx1) ? (1.f - wy) * wx : 0.f;
  wv.z = (vy1 && vx0) ? wy * (1.f - wx) : 0.f;
  wv.w = (vy1 && vx1) ? wy * wx : 0.f;
  cidx[t] = id;
  cwt[t] = wv;
}

// ---------------- K4: barrier-free sampler: Pb[kcl][m][32] bf16, one K-half ----------------
// grid 9216 blocks: b = blk&7 (XCD x-locality), r = blk>>3: kcl = r%18, ho = r/18.
// thread: wo = tid>>2, octet = tid&3 -> 8 cins; writes 16B, block covers 16KB contiguous.
__global__ __launch_bounds__(256) void sampler_kernel(
    const float* __restrict__ x, const short4* __restrict__ cidx,
    const float4* __restrict__ cwt, short* __restrict__ Pb, int half) {
  int blk = blockIdx.x;
  int b = blk & 7;
  int r = blk >> 3;                  // 0..1151
  int kcl = r % KCH;
  int ho = r / KCH;
  int tid = threadIdx.x;
  int wo = tid >> 2, octet = tid & 3;
  int m = b * HW + ho * 64 + wo;
  int kcg = half * KCH + kcl;        // 0..35
  int kk = kcg >> 2;
  int cin = (kcg & 3) * 32 + octet * 8;
  short4 id = cidx[kk * M_ + m];
  float4 wv = cwt[kk * M_ + m];
  const float* xp = x + (b * CIN + cin) * HW;
  union { short s[8]; int4 v; } bu;
#pragma unroll
  for (int c = 0; c < 8; ++c) {
    const float* p = xp + c * HW;
    float vsm = wv.x * p[(int)id.x] + wv.y * p[(int)id.y]
              + wv.z * p[(int)id.z] + wv.w * p[(int)id.w];
    bu.s[c] = f2bf(vsm);
  }
  *(int4*)&Pb[(kcl * M_ + m) * 32 + octet * 8] = bu.v;
}

// ---------------- K5: clean bf16 MFMA GEMM over one K-half ----------------
// blockIdx = mt*2 + ct: tile 128 cout x 128 m; 256 threads = 4 waves of 64x64.
// BK=32 chunks from blocked Wb/Pb (contiguous int4 staging); round-2-proven
// LDS layout (pad 40) and fragment indexing. half==1 accumulates into y.
__global__ __launch_bounds__(256, 4) void gemm_kernel(
    const short* __restrict__ Wb, const short* __restrict__ Pb,
    float* __restrict__ y, int half) {
  __shared__ __align__(16) short sa[128 * 40];   // [cout][k] pad 40
  __shared__ __align__(16) short sb[128 * 40];   // [m][k]    pad 40

  int tid = threadIdx.x;
  int ct = blockIdx.x & 1;
  int mt = blockIdx.x >> 1;          // 0..255
  int cout0 = ct * 128;
  int m0 = mt * 128;

  int lane = tid & 63, wave = tid >> 6;
  int quad = lane >> 4, l16 = lane & 15;
  int wm = (wave & 1) << 6;          // cout sub-tile 0/64
  int wnm = (wave >> 1) << 6;        // m sub-tile 0/64

  int srow = tid >> 1;               // staging row 0..127
  int koff = (tid & 1) << 4;         // 0 or 16 shorts

  f32x4 zero = {0.f, 0.f, 0.f, 0.f};
  f32x4 acc[4][4];
#pragma unroll
  for (int i = 0; i < 4; ++i)
#pragma unroll
    for (int j = 0; j < 4; ++j) acc[i][j] = zero;

  for (int kcl = 0; kcl < KCH; ++kcl) {
    int kcg = half * KCH + kcl;
    // contiguous streaming loads (issued before barrier; overlap via co-resident blocks)
    const int4* asrc = (const int4*)&Wb[(kcg * 256 + cout0 + srow) * 32 + koff];
    int4 aw0 = asrc[0];
    int4 aw1 = asrc[1];
    const int4* bsrc = (const int4*)&Pb[(kcl * M_ + m0 + srow) * 32 + koff];
    int4 bw0 = bsrc[0];
    int4 bw1 = bsrc[1];
    __syncthreads();   // previous chunk's frag reads done (WAR)
    *(int4*)&sa[srow * 40 + koff]     = aw0;
    *(int4*)&sa[srow * 40 + koff + 8] = aw1;
    *(int4*)&sb[srow * 40 + koff]     = bw0;
    *(int4*)&sb[srow * 40 + koff + 8] = bw1;
    __syncthreads();   // tile ready (RAW)

    bf16x8 af[4], bfr[4];
#pragma unroll
    for (int i = 0; i < 4; ++i)
      af[i] = *(const bf16x8*)&sa[(wm + i * 16 + l16) * 40 + quad * 8];
#pragma unroll
    for (int j = 0; j < 4; ++j)
      bfr[j] = *(const bf16x8*)&sb[(wnm + j * 16 + l16) * 40 + quad * 8];
#pragma unroll
    for (int i = 0; i < 4; ++i)
#pragma unroll
      for (int j = 0; j < 4; ++j)
        acc[i][j] = __builtin_amdgcn_mfma_f32_16x16x32_bf16(af[i], bfr[j], acc[i][j], 0, 0, 0);
  }

  // epilogue: y[(b,cout,ho,wo)]; half 0 writes, half 1 accumulates.
  // (dconv bias omitted: exactly cancelled by BN mean-subtraction)
#pragma unroll
  for (int i = 0; i < 4; ++i) {
    int crow = cout0 + wm + i * 16 + quad * 4;
#pragma unroll
    for (int j = 0; j < 4; ++j) {
      int m = m0 + wnm + j * 16 + l16;
      int b = m >> 12;
      float* yp = y + (b * COUT + crow) * HW + (m & 4095);
      if (half == 0) {
#pragma unroll
        for (int r2 = 0; r2 < 4; ++r2)
          yp[r2 * HW] = acc[i][j][r2];
      } else {
#pragma unroll
        for (int r2 = 0; r2 < 4; ++r2)
          yp[r2 * HW] += acc[i][j][r2];
      }
    }
  }
}

// ---------------- K6: BN batch stats (proven) ----------------
__global__ __launch_bounds__(256) void bn_stats_kernel(
    const float* __restrict__ y, float* __restrict__ mean, float* __restrict__ invstd) {
  int c = blockIdx.x;
  int tid = threadIdx.x;
  float s = 0.f, s2 = 0.f;
  for (int b = 0; b < B_; ++b) {
    const float4* p = (const float4*)(y + (b * COUT + c) * HW);
    for (int i = tid; i < HW / 4; i += 256) {
      float4 v = p[i];
      s += v.x + v.y + v.z + v.w;
      s2 = fmaf(v.x, v.x, s2); s2 = fmaf(v.y, v.y, s2);
      s2 = fmaf(v.z, v.z, s2); s2 = fmaf(v.w, v.w, s2);
    }
  }
#pragma unroll
  for (int o = 32; o > 0; o >>= 1) {
    s  += __shfl_down(s, o);
    s2 += __shfl_down(s2, o);
  }
  __shared__ float rs[4], rs2[4];
  int wid = tid >> 6, ln = tid & 63;
  if (ln == 0) { rs[wid] = s; rs2[wid] = s2; }
  __syncthreads();
  if (tid == 0) {
    float S  = rs[0] + rs[1] + rs[2] + rs[3];
    float S2 = rs2[0] + rs2[1] + rs2[2] + rs2[3];
    float m = S / 32768.f;
    float var = S2 / 32768.f - m * m;
    mean[c] = m;
    invstd[c] = rsqrtf(var + 1e-5f);
  }
}

// ---------------- K7: BN apply + SiLU, in place on y (= d_out) ----------------
__global__ __launch_bounds__(256) void bn_silu_kernel(
    float* __restrict__ y, const float* __restrict__ mean,
    const float* __restrict__ invstd, const float* __restrict__ gamma,
    const float* __restrict__ beta) {
  int i4 = blockIdx.x * 256 + threadIdx.x;   // 2097152 float4s
  int c = (i4 >> 10) & 255;
  float4 v = ((const float4*)y)[i4];
  float m = mean[c], sc = invstd[c] * gamma[c], bt = beta[c];
  float t0 = (v.x - m) * sc + bt;
  float t1 = (v.y - m) * sc + bt;
  float t2 = (v.z - m) * sc + bt;
  float t3 = (v.w - m) * sc + bt;
  float4 o;
  o.x = t0 / (1.f + expf(-t0));
  o.y = t1 / (1.f + expf(-t1));
  o.z = t2 / (1.f + expf(-t2));
  o.w = t3 / (1.f + expf(-t3));
  ((float4*)y)[i4] = o;
}

extern "C" void kernel_launch(void* const* d_in, const int* in_sizes, int n_in,
                              void* d_out, int out_size, void* d_ws, size_t ws_size,
                              hipStream_t stream) {
  const float* x     = (const float*)d_in[0];
  const float* ow    = (const float*)d_in[1];
  const float* ob    = (const float*)d_in[2];
  const float* dw    = (const float*)d_in[3];
  // d_in[4] = dconv bias: cancelled exactly by BN mean-subtraction
  const float* gamma = (const float*)d_in[5];
  const float* beta  = (const float*)d_in[6];
  float* y = (float*)d_out;                  // 8*256*4096 f32 — used as y buffer

  // ws layout (float offsets), total 13,713,920 floats = 54.9 MB
  float*  ws   = (float*)d_ws;
  short*  Pb   = (short*)ws;                 // 18*32768*32 shorts = 9437184 floats
  float*  offp = ws + 9437184;               // 2359296
  short4* cidx = (short4*)(ws + 11796480);   // 9*32768 short4 = 589824 floats
  float4* cwt  = (float4*)(ws + 12386304);   // 9*32768 float4 = 1179648 floats
  short*  Wb   = (short*)(ws + 13565952);    // 294912 shorts = 147456 floats
  float*  mean   = ws + 13713408;            // 256
  float*  invstd = ws + 13713664;            // 256

  offset_conv_kernel<<<512, 256, 0, stream>>>(x, ow, ob, offp);
  wt_cvt_kernel<<<1152, 256, 0, stream>>>(dw, Wb);
  coeff_kernel<<<1152, 256, 0, stream>>>(offp, cidx, cwt);

  sampler_kernel<<<9216, 256, 0, stream>>>(x, cidx, cwt, Pb, 0);
  gemm_kernel<<<512, 256, 0, stream>>>(Wb, Pb, y, 0);
  sampler_kernel<<<9216, 256, 0, stream>>>(x, cidx, cwt, Pb, 1);
  gemm_kernel<<<512, 256, 0, stream>>>(Wb, Pb, y, 1);

  bn_stats_kernel<<<256, 256, 0, stream>>>(y, mean, invstd);
  bn_silu_kernel<<<8192, 256, 0, stream>>>(y, mean, invstd, gamma, beta);
}

// Round 7
// 248.513 us; speedup vs baseline: 1.2541x; 1.2541x over previous
//
#include <hip/hip_runtime.h>
#include <hip/hip_bf16.h>
#include <math.h>

// (B,Cin,H,W)=(8,128,64,64), Cout=256, K=3, stride=1, pad=1, dil=1
#define B_    8
#define CIN   128
#define Hx    64
#define Wx    64
#define COUT  256
#define HW    4096
#define KTOT  1152      // CIN*9
#define NOFF  18
#define M_    32768     // B*HW
#define OFFSEG (B_ * NOFF * HW)   // 589824 floats per cin-segment partial
#define KCH   18        // K-chunks per half (chunk = 32 k)

typedef short bf16x8 __attribute__((ext_vector_type(8)));
typedef float f32x4  __attribute__((ext_vector_type(4)));

static __device__ __forceinline__ short f2bf(float f) {
  __hip_bfloat16 h = __float2bfloat16(f);
  return *reinterpret_cast<short*>(&h);
}

// ---------------- K1: offset conv ----------------
// block = (chalf 0..1, seg 0..3, r 0..127); thread -> (b,ho,wo), computes 9 channels
// over 32 cins. Weights staged in LDS (wave-uniform broadcast reads); acc[9] stays
// in VGPRs (round-6 acc[18] spilled: VGPR_Count=24).
__global__ __launch_bounds__(256, 4) void offset_conv_kernel(
    const float* __restrict__ x, const float* __restrict__ ow,
    const float* __restrict__ ob, float* __restrict__ offp) {
  __shared__ float lds_w[9 * 288];          // 9ch x 32cin x 9tap = 10.4 KB
  int blk = blockIdx.x;
  int r = blk & 127, seg = (blk >> 7) & 3, chalf = blk >> 9;
  int tid = threadIdx.x;
  for (int i = tid; i < 9 * 288; i += 256) {
    int c = i / 288, rem = i - c * 288;
    lds_w[i] = ow[(chalf * 9 + c) * KTOT + seg * 288 + rem];
  }
  __syncthreads();

  int v = r * 256 + tid;                    // 0..32767
  int wo = v & 63, ho = (v >> 6) & 63, b = v >> 12;
  float acc[9];
#pragma unroll
  for (int c = 0; c < 9; ++c) acc[c] = 0.f;
  const float* xb = x + (b * CIN + seg * 32) * HW;
  for (int ci = 0; ci < 32; ++ci) {
    const float* xp = xb + ci * HW;
    float win[9];
#pragma unroll
    for (int ky = 0; ky < 3; ++ky) {
      int iy = ho - 1 + ky;
      bool rok = (iy >= 0) & (iy < Hx);
      const float* rowp = xp + iy * Wx;
#pragma unroll
      for (int kx = 0; kx < 3; ++kx) {
        int ix = wo - 1 + kx;
        win[ky * 3 + kx] = (rok & (ix >= 0) & (ix < Wx)) ? rowp[ix] : 0.f;
      }
    }
    const float* wl = lds_w + ci * 9;
#pragma unroll
    for (int c = 0; c < 9; ++c) {
#pragma unroll
      for (int t = 0; t < 9; ++t)
        acc[c] = fmaf(win[t], wl[c * 288 + t], acc[c]);
    }
  }
  float* op = offp + seg * OFFSEG + (b * NOFF + chalf * 9) * HW + ho * 64 + wo;
#pragma unroll
  for (int c = 0; c < 9; ++c)
    op[c * HW] = acc[c] + ((seg == 0) ? ob[chalf * 9 + c] : 0.f);
}

// ---------------- K2: weight -> bf16 blocked Wb[kc][cout][32] (proven) ----------------
__global__ __launch_bounds__(256) void wt_cvt_kernel(
    const float* __restrict__ w, short* __restrict__ Wb) {
  int t = blockIdx.x * 256 + threadIdx.x;   // 294912
  int ki = t & 31;
  int cout = (t >> 5) & 255;
  int kc = t >> 13;                         // 0..35
  int k = kc * 32 + ki;
  int kk = k >> 7, cin = k & 127;
  Wb[t] = f2bf(w[(cout * CIN + cin) * 9 + kk]);
}

// ---------------- K3: bilinear coefficient tables (proven) ----------------
__global__ __launch_bounds__(256) void coeff_kernel(
    const float* __restrict__ offp, short4* __restrict__ cidx, float4* __restrict__ cwt) {
  int t = blockIdx.x * 256 + threadIdx.x;   // 9*32768
  int m = t & (M_ - 1);
  int kk = t >> 15;                         // 0..8
  int b = m >> 12, ho = (m >> 6) & 63, wo = m & 63;
  int base = (b * NOFF + 2 * kk) * HW + (m & 4095);
  float dy = offp[base] + offp[base + OFFSEG] + offp[base + 2 * OFFSEG] + offp[base + 3 * OFFSEG];
  int base2 = base + HW;
  float dx = offp[base2] + offp[base2 + OFFSEG] + offp[base2 + 2 * OFFSEG] + offp[base2 + 3 * OFFSEG];
  float sy = (float)(ho - 1 + kk / 3) + dy;
  float sx = (float)(wo - 1 + kk % 3) + dx;
  float fy = floorf(sy), fx = floorf(sx);
  int y0 = (int)fy, x0 = (int)fx;
  float wy = sy - fy, wx = sx - fx;
  int y1 = y0 + 1, x1 = x0 + 1;
  int cy0 = min(max(y0, 0), Hx - 1), cy1 = min(max(y1, 0), Hx - 1);
  int cx0 = min(max(x0, 0), Wx - 1), cx1 = min(max(x1, 0), Wx - 1);
  bool vy0 = (y0 >= 0) & (y0 < Hx), vy1 = (y1 >= 0) & (y1 < Hx);
  bool vx0 = (x0 >= 0) & (x0 < Wx), vx1 = (x1 >= 0) & (x1 < Wx);
  short4 id;
  id.x = (short)(cy0 * Wx + cx0); id.y = (short)(cy0 * Wx + cx1);
  id.z = (short)(cy1 * Wx + cx0); id.w = (short)(cy1 * Wx + cx1);
  float4 wv;
  wv.x = (vy0 && vx0) ? (1.f - wy) * (1.f - wx) : 0.f;
  wv.y = (vy0 && vx1) ? (1.f - wy) * wx : 0.f;
  wv.z = (vy1 && vx0) ? wy * (1.f - wx) : 0.f;
  wv.w = (vy1 && vx1) ? wy * wx : 0.f;
  cidx[t] = id;
  cwt[t] = wv;
}

// ---------------- K4: LDS-plane sampler, one K-half ----------------
// block = (b = blk&7, g4 = blk>>3): stages x planes for cins 4*g4..4*g4+3 into LDS
// (64 KB), then gathers from LDS for the half's taps of this cin-quarter.
// Pb layout: Pb[e][kcl][m][4] shorts (e = cin_local/4 = g4&7) -> int2 writes,
// 16B/lane-pair contiguous across m.
__global__ __launch_bounds__(256) void sampler_kernel(
    const float* __restrict__ x, const short4* __restrict__ cidx,
    const float4* __restrict__ cwt, short* __restrict__ Pb, int half) {
  __shared__ float lds_x[4 * HW];           // 65536 B
  int blk = blockIdx.x;
  int b = blk & 7;
  int g4 = blk >> 3;                        // 0..31
  int cinq = g4 >> 3;                       // chunk cin-quarter
  int e = g4 & 7;                           // 4-cin slot within chunk
  int tid = threadIdx.x;

  // stage 4 planes (contiguous 64 KB from x)
  const float4* src = (const float4*)(x + (b * CIN + g4 * 4) * HW);
  float4* dst = (float4*)lds_x;
#pragma unroll
  for (int it = 0; it < 16; ++it)
    dst[it * 256 + tid] = src[it * 256 + tid];
  __syncthreads();

  for (int kk = 0; kk < 9; ++kk) {
    int kcg = kk * 4 + cinq;
    if ((kcg / KCH) != half) continue;      // block-uniform
    int kcl = kcg - half * KCH;
#pragma unroll
    for (int it = 0; it < 16; ++it) {
      int pos = it * 256 + tid;
      int m = b * HW + pos;
      short4 id = cidx[kk * M_ + m];
      float4 wv = cwt[kk * M_ + m];
      union { short s[4]; int2 v; } bu;
#pragma unroll
      for (int c = 0; c < 4; ++c) {
        const float* pl = lds_x + c * HW;
        float vsm = wv.x * pl[(int)id.x] + wv.y * pl[(int)id.y]
                  + wv.z * pl[(int)id.z] + wv.w * pl[(int)id.w];
        bu.s[c] = f2bf(vsm);
      }
      *(int2*)&Pb[((e * KCH + kcl) * M_ + m) * 4] = bu.v;
    }
  }
}

// ---------------- K5: bf16 MFMA GEMM over one K-half (round-6 body) ----------------
// blockIdx = mt*2 + ct: tile 128 cout x 128 m; 256 threads = 4 waves of 64x64.
// B-source = Pb[e][kcl][m][4]; k-order within chunk unchanged (matches Wb).
__global__ __launch_bounds__(256, 4) void gemm_kernel(
    const short* __restrict__ Wb, const short* __restrict__ Pb,
    float* __restrict__ y, int half) {
  __shared__ __align__(16) short sa[128 * 40];   // [cout][k] pad 40
  __shared__ __align__(16) short sb[128 * 40];   // [m][k]    pad 40

  int tid = threadIdx.x;
  int ct = blockIdx.x & 1;
  int mt = blockIdx.x >> 1;          // 0..255
  int cout0 = ct * 128;
  int m0 = mt * 128;

  int lane = tid & 63, wave = tid >> 6;
  int quad = lane >> 4, l16 = lane & 15;
  int wm = (wave & 1) << 6;          // cout sub-tile 0/64
  int wnm = (wave >> 1) << 6;        // m sub-tile 0/64

  int srow = tid >> 1;               // staging row 0..127
  int koff = (tid & 1) << 4;         // 0 or 16 shorts
  int e0 = koff >> 2;                // 0 or 4

  f32x4 zero = {0.f, 0.f, 0.f, 0.f};
  f32x4 acc[4][4];
#pragma unroll
  for (int i = 0; i < 4; ++i)
#pragma unroll
    for (int j = 0; j < 4; ++j) acc[i][j] = zero;

  for (int kcl = 0; kcl < KCH; ++kcl) {
    int kcg = half * KCH + kcl;
    const int4* asrc = (const int4*)&Wb[(kcg * 256 + cout0 + srow) * 32 + koff];
    int4 aw0 = asrc[0];
    int4 aw1 = asrc[1];
    int mrow = m0 + srow;
    int2 bw0 = *(const int2*)&Pb[((e0 + 0) * KCH + kcl) * (M_ * 4) + mrow * 4];
    int2 bw1 = *(const int2*)&Pb[((e0 + 1) * KCH + kcl) * (M_ * 4) + mrow * 4];
    int2 bw2 = *(const int2*)&Pb[((e0 + 2) * KCH + kcl) * (M_ * 4) + mrow * 4];
    int2 bw3 = *(const int2*)&Pb[((e0 + 3) * KCH + kcl) * (M_ * 4) + mrow * 4];
    __syncthreads();   // previous chunk's frag reads done (WAR)
    *(int4*)&sa[srow * 40 + koff]     = aw0;
    *(int4*)&sa[srow * 40 + koff + 8] = aw1;
    *(int2*)&sb[srow * 40 + koff]      = bw0;
    *(int2*)&sb[srow * 40 + koff + 4]  = bw1;
    *(int2*)&sb[srow * 40 + koff + 8]  = bw2;
    *(int2*)&sb[srow * 40 + koff + 12] = bw3;
    __syncthreads();   // tile ready (RAW)

    bf16x8 af[4], bfr[4];
#pragma unroll
    for (int i = 0; i < 4; ++i)
      af[i] = *(const bf16x8*)&sa[(wm + i * 16 + l16) * 40 + quad * 8];
#pragma unroll
    for (int j = 0; j < 4; ++j)
      bfr[j] = *(const bf16x8*)&sb[(wnm + j * 16 + l16) * 40 + quad * 8];
#pragma unroll
    for (int i = 0; i < 4; ++i)
#pragma unroll
      for (int j = 0; j < 4; ++j)
        acc[i][j] = __builtin_amdgcn_mfma_f32_16x16x32_bf16(af[i], bfr[j], acc[i][j], 0, 0, 0);
  }

  // epilogue: y[(b,cout,ho,wo)]; half 0 writes, half 1 accumulates.
  // (dconv bias omitted: exactly cancelled by BN mean-subtraction)
#pragma unroll
  for (int i = 0; i < 4; ++i) {
    int crow = cout0 + wm + i * 16 + quad * 4;
#pragma unroll
    for (int j = 0; j < 4; ++j) {
      int m = m0 + wnm + j * 16 + l16;
      int b = m >> 12;
      float* yp = y + (b * COUT + crow) * HW + (m & 4095);
      if (half == 0) {
#pragma unroll
        for (int r2 = 0; r2 < 4; ++r2)
          yp[r2 * HW] = acc[i][j][r2];
      } else {
#pragma unroll
        for (int r2 = 0; r2 < 4; ++r2)
          yp[r2 * HW] += acc[i][j][r2];
      }
    }
  }
}

// ---------------- K6: BN batch stats (proven) ----------------
__global__ __launch_bounds__(256) void bn_stats_kernel(
    const float* __restrict__ y, float* __restrict__ mean, float* __restrict__ invstd) {
  int c = blockIdx.x;
  int tid = threadIdx.x;
  float s = 0.f, s2 = 0.f;
  for (int b = 0; b < B_; ++b) {
    const float4* p = (const float4*)(y + (b * COUT + c) * HW);
    for (int i = tid; i < HW / 4; i += 256) {
      float4 v = p[i];
      s += v.x + v.y + v.z + v.w;
      s2 = fmaf(v.x, v.x, s2); s2 = fmaf(v.y, v.y, s2);
      s2 = fmaf(v.z, v.z, s2); s2 = fmaf(v.w, v.w, s2);
    }
  }
#pragma unroll
  for (int o = 32; o > 0; o >>= 1) {
    s  += __shfl_down(s, o);
    s2 += __shfl_down(s2, o);
  }
  __shared__ float rs[4], rs2[4];
  int wid = tid >> 6, ln = tid & 63;
  if (ln == 0) { rs[wid] = s; rs2[wid] = s2; }
  __syncthreads();
  if (tid == 0) {
    float S  = rs[0] + rs[1] + rs[2] + rs[3];
    float S2 = rs2[0] + rs2[1] + rs2[2] + rs2[3];
    float m = S / 32768.f;
    float var = S2 / 32768.f - m * m;
    mean[c] = m;
    invstd[c] = rsqrtf(var + 1e-5f);
  }
}

// ---------------- K7: BN apply + SiLU, in place on y (= d_out) (proven) ----------------
__global__ __launch_bounds__(256) void bn_silu_kernel(
    float* __restrict__ y, const float* __restrict__ mean,
    const float* __restrict__ invstd, const float* __restrict__ gamma,
    const float* __restrict__ beta) {
  int i4 = blockIdx.x * 256 + threadIdx.x;   // 2097152 float4s
  int c = (i4 >> 10) & 255;
  float4 v = ((const float4*)y)[i4];
  float m = mean[c], sc = invstd[c] * gamma[c], bt = beta[c];
  float t0 = (v.x - m) * sc + bt;
  float t1 = (v.y - m) * sc + bt;
  float t2 = (v.z - m) * sc + bt;
  float t3 = (v.w - m) * sc + bt;
  float4 o;
  o.x = t0 / (1.f + expf(-t0));
  o.y = t1 / (1.f + expf(-t1));
  o.z = t2 / (1.f + expf(-t2));
  o.w = t3 / (1.f + expf(-t3));
  ((float4*)y)[i4] = o;
}

extern "C" void kernel_launch(void* const* d_in, const int* in_sizes, int n_in,
                              void* d_out, int out_size, void* d_ws, size_t ws_size,
                              hipStream_t stream) {
  const float* x     = (const float*)d_in[0];
  const float* ow    = (const float*)d_in[1];
  const float* ob    = (const float*)d_in[2];
  const float* dw    = (const float*)d_in[3];
  // d_in[4] = dconv bias: cancelled exactly by BN mean-subtraction
  const float* gamma = (const float*)d_in[5];
  const float* beta  = (const float*)d_in[6];
  float* y = (float*)d_out;                  // 8*256*4096 f32 — used as y buffer

  // ws layout (float offsets), total 13,713,920 floats = 54.9 MB
  float*  ws   = (float*)d_ws;
  short*  Pb   = (short*)ws;                 // 8*18*32768*4 shorts = 9437184 floats
  float*  offp = ws + 9437184;               // 2359296
  short4* cidx = (short4*)(ws + 11796480);   // 9*32768 short4 = 589824 floats
  float4* cwt  = (float4*)(ws + 12386304);   // 9*32768 float4 = 1179648 floats
  short*  Wb   = (short*)(ws + 13565952);    // 294912 shorts = 147456 floats
  float*  mean   = ws + 13713408;            // 256
  float*  invstd = ws + 13713664;            // 256

  offset_conv_kernel<<<1024, 256, 0, stream>>>(x, ow, ob, offp);
  wt_cvt_kernel<<<1152, 256, 0, stream>>>(dw, Wb);
  coeff_kernel<<<1152, 256, 0, stream>>>(offp, cidx, cwt);

  sampler_kernel<<<256, 256, 0, stream>>>(x, cidx, cwt, Pb, 0);
  gemm_kernel<<<512, 256, 0, stream>>>(Wb, Pb, y, 0);
  sampler_kernel<<<256, 256, 0, stream>>>(x, cidx, cwt, Pb, 1);
  gemm_kernel<<<512, 256, 0, stream>>>(Wb, Pb, y, 1);

  bn_stats_kernel<<<256, 256, 0, stream>>>(y, mean, invstd);
  bn_silu_kernel<<<8192, 256, 0, stream>>>(y, mean, invstd, gamma, beta);
}